// Round 1
// 133.298 us; speedup vs baseline: 1.0489x; 1.0489x over previous
//
#include <hip/hip_runtime.h>
#include <math.h>

#define NFM_B 16384
#define NFM_F 39
#define NFM_E 16
#define NFM_H 200
#define TR    16          // rows per block (full M=16 MFMA tile, no dead rows)
#define KPAD  232         // padded K row stride (shorts); 464B, 16B-aligned
#define NT    13          // n-tiles of 16 (208 >= 200)
#define VOCAB 1000000

typedef short short8   __attribute__((ext_vector_type(8)));   // 8 bf16 = 4 VGPRs
typedef short short4_t __attribute__((ext_vector_type(4)));
typedef float floatx4  __attribute__((ext_vector_type(4)));

__device__ __forceinline__ short f2bf(float x) {   // fp32 -> bf16 RNE
    union { float f; unsigned u; } a; a.f = x;
    unsigned r = a.u + 0x7FFF + ((a.u >> 16) & 1);
    return (short)(r >> 16);
}

// d_ws layout (shorts): W0/W1/W2 bf16 B-fragments only.
// (w is read as fp32 directly in the main kernel -- no bf16 w table.)
#define W0F_OFF  0
#define W0F_SZ   (NT * 1 * 64 * 8)          // 6656
#define W1F_OFF  (W0F_OFF + W0F_SZ)
#define W1F_SZ   (NT * 7 * 64 * 8)          // 46592
#define W2F_OFF  (W1F_OFF + W1F_SZ)
#define W2F_SZ   (NT * 7 * 64 * 8)
#define WS_FRAGS (W2F_OFF + W2F_SZ)         // 99840 shorts (~200 KB)
#define FRAG_BLOCKS  ((WS_FRAGS + 255) / 256)           // 390

// Prep: build bf16 weight fragments for the three MFMA layers.
__global__ __launch_bounds__(256)
void nfm_prep_kernel(const float* __restrict__ w0,
                     const float* __restrict__ w1,
                     const float* __restrict__ w2,
                     short* __restrict__ ws)
{
    const int idx = blockIdx.x * 256 + threadIdx.x;
    if (idx >= WS_FRAGS) return;
    float val;
    if (idx < W1F_OFF) {
        const int rem = idx;
        const int j = rem & 7, lane = (rem >> 3) & 63, tile = rem >> 9;
        const int k = (lane >> 4) * 8 + j;
        const int n = tile * 16 + (lane & 15);
        val = (k < NFM_E && n < NFM_H) ? w0[k * NFM_H + n] : 0.f;
    } else if (idx < W2F_OFF) {
        const int rem = idx - W1F_OFF;
        const int j = rem & 7, lane = (rem >> 3) & 63;
        const int kt = rem >> 9;
        const int ks = kt % 7, tile = kt / 7;
        const int k = ks * 32 + (lane >> 4) * 8 + j;
        const int n = tile * 16 + (lane & 15);
        val = (k < NFM_H && n < NFM_H) ? w1[k * NFM_H + n] : 0.f;
    } else {
        const int rem = idx - W2F_OFF;
        const int j = rem & 7, lane = (rem >> 3) & 63;
        const int kt = rem >> 9;
        const int ks = kt % 7, tile = kt / 7;
        const int k = ks * 32 + (lane >> 4) * 8 + j;
        const int n = tile * 16 + (lane & 15);
        val = (k < NFM_H && n < NFM_H) ? w2[k * NFM_H + n] : 0.f;
    }
    ws[idx] = f2bf(val);
}

// 16 rows/block: 16 lanes per row, 10 field-slots per lane (4 fs x 10 it = 40 >= 39).
// __launch_bounds__(256,4): grid is 1024 blocks -> 4 blocks/CU max anyway;
// the 128-VGPR cap leaves room for the 10 in-flight float4 gathers.
__global__ __launch_bounds__(256, 4)
void nfm_main_kernel(
    const int*   __restrict__ feat_ids,   // [B,F]
    const float* __restrict__ feat_vals,  // [B,F]
    const float* __restrict__ v,          // [VOCAB,16] fp32
    const float* __restrict__ w,          // [VOCAB,1]  fp32 (L2-resident, 4 MB)
    const float* __restrict__ bglob,      // [1]
    const float* __restrict__ b0,
    const float* __restrict__ b1,
    const float* __restrict__ b2,
    const short* __restrict__ ws,         // bf16 weight fragments
    float* __restrict__ out)              // [B]
{
    __shared__ __attribute__((aligned(16))) short hbfA[16 * KPAD]; // 7424 B
    __shared__ __attribute__((aligned(16))) short hbfB[16 * KPAD];
    __shared__ float rowsumW[4][16];
    __shared__ float lrS[TR];

    const int tid  = threadIdx.x;
    const int row0 = blockIdx.x * TR;
    const int lane = tid & 63;
    const int wv   = tid >> 6;     // wave 0..3
    const int lq   = lane >> 4;    // quad 0..3
    const int ln   = lane & 15;

    const short* Wfb = ws;

    // ---------- issue all gather loads up front (latency overlapped by
    // the LDS zero-fill below; no staging barrier in the way) ----------
    const int rr  = tid >> 4;              // row 0..15 within block
    const int l16 = tid & 15;
    const int eg  = l16 & 3;               // e-group: 4 floats each
    const int fs  = l16 >> 2;              // field slot 0..3
    const long rbase = (long)(row0 + rr) * NFM_F;

    int   idv[10]; float vlv[10];
#pragma unroll
    for (int it = 0; it < 10; ++it) {
        const int f = fs + it * 4;         // fs=3,it=9 -> 39 OOB
        const bool ok = f < NFM_F;
        idv[it] = ok ? feat_ids [rbase + f] : 0;
        vlv[it] = ok ? feat_vals[rbase + f] : 0.f;
    }
    float4 ve[10]; float wg[10];
#pragma unroll
    for (int it = 0; it < 10; ++it) {
        ve[it] = *(const float4*)&v[(long)idv[it] * NFM_E + eg * 4];
        wg[it] = w[idv[it]];               // 4 lanes/addr broadcast; L2-resident
    }

    // Zero both activation buffers (K-pad cols, fm pad cols 16..31) while the
    // gather loads are in flight.
    {
        short8 z8 = {0, 0, 0, 0, 0, 0, 0, 0};
        short8* pA = (short8*)hbfA;
        short8* pB = (short8*)hbfB;
        for (int i = tid; i < 464; i += 256) { pA[i] = z8; pB[i] = z8; }
    }
    __syncthreads();   // zero-fill visible before fm stores land

    // ---------- FM pooling + LR ----------
    {
        floatx4 xv = {0.f, 0.f, 0.f, 0.f}, x2 = {0.f, 0.f, 0.f, 0.f};
#pragma unroll
        for (int it = 0; it < 10; ++it) {
            const float val = vlv[it];
            const float t0 = val * ve[it].x, t1 = val * ve[it].y;
            const float t2 = val * ve[it].z, t3 = val * ve[it].w;
            xv[0] += t0; xv[1] += t1; xv[2] += t2; xv[3] += t3;
            x2[0] = fmaf(t0, t0, x2[0]); x2[1] = fmaf(t1, t1, x2[1]);
            x2[2] = fmaf(t2, t2, x2[2]); x2[3] = fmaf(t3, t3, x2[3]);
        }
        // reduce across the 4 field-slot lanes (same eg) within each row
#pragma unroll
        for (int off = 4; off <= 8; off <<= 1) {
#pragma unroll
            for (int c = 0; c < 4; ++c) {
                xv[c] += __shfl_xor(xv[c], off, 16);
                x2[c] += __shfl_xor(x2[c], off, 16);
            }
        }
        if (fs == 0) {                      // lanes l16 = eg = 0..3
            short4_t fm4;
#pragma unroll
            for (int c = 0; c < 4; ++c)
                fm4[c] = f2bf(0.5f * (xv[c] * xv[c] - x2[c]));
            *(short4_t*)&hbfB[rr * KPAD + eg * 4] = fm4;
        }
        // LR: eg==0 lanes cover every field exactly once (f = fs + it*4)
        float lr = 0.f;
#pragma unroll
        for (int it = 0; it < 10; ++it)
            lr = fmaf(vlv[it], wg[it], lr);
        lr = (eg == 0) ? lr : 0.f;
        lr += __shfl_xor(lr, 4, 16);
        lr += __shfl_xor(lr, 8, 16);
        if (l16 == 0) lrS[rr] = lr;
    }
    __syncthreads();

    // ---------- L0: fm(bf16, K=32) @ W0f -> hbfA ----------
    {
        const short8 af = *(const short8*)&hbfB[ln * KPAD + lq * 8];
        const short* Wf = Wfb + W0F_OFF;
        for (int t = wv; t < NT; t += 4) {
            const int n = t * 16 + ln;
            const float bj = (n < NFM_H) ? b0[n] : 0.f;
            floatx4 acc = {bj, bj, bj, bj};
            const short8 bf = *(const short8*)&Wf[(t * 64 + lane) * 8];
            acc = __builtin_amdgcn_mfma_f32_16x16x32_bf16(af, bf, acc, 0, 0, 0);
#pragma unroll
            for (int rg = 0; rg < 4; ++rg)          // n>=200 computes exact 0
                hbfA[(lq * 4 + rg) * KPAD + n] = f2bf(fmaxf(acc[rg], 0.f));
        }
    }
    __syncthreads();

    // ---------- L1: hbfA @ W1f -> hbfB ----------
    {
        short8 af[7];
#pragma unroll
        for (int ks = 0; ks < 7; ++ks)
            af[ks] = *(const short8*)&hbfA[ln * KPAD + ks * 32 + lq * 8];
        const short* Wf = Wfb + W1F_OFF;
        for (int t = wv; t < NT; t += 4) {
            const int n = t * 16 + ln;
            const float bj = (n < NFM_H) ? b1[n] : 0.f;
            floatx4 acc = {bj, bj, bj, bj};
#pragma unroll
            for (int ks = 0; ks < 7; ++ks) {
                const short8 bf = *(const short8*)&Wf[((t * 7 + ks) * 64 + lane) * 8];
                acc = __builtin_amdgcn_mfma_f32_16x16x32_bf16(af[ks], bf, acc, 0, 0, 0);
            }
#pragma unroll
            for (int rg = 0; rg < 4; ++rg)
                hbfB[(lq * 4 + rg) * KPAD + n] = f2bf(fmaxf(acc[rg], 0.f));
        }
    }
    __syncthreads();

    // ---------- L2: hbfB @ W2f -> row sums (no materialization) ----------
    {
        short8 af[7];
#pragma unroll
        for (int ks = 0; ks < 7; ++ks)
            af[ks] = *(const short8*)&hbfB[ln * KPAD + ks * 32 + lq * 8];
        const short* Wf = Wfb + W2F_OFF;
        float rs[4] = {0.f, 0.f, 0.f, 0.f};
        for (int t = wv; t < NT; t += 4) {
            const int n = t * 16 + ln;
            const float bj = (n < NFM_H) ? b2[n] : 0.f;
            floatx4 acc = {bj, bj, bj, bj};
#pragma unroll
            for (int ks = 0; ks < 7; ++ks) {
                const short8 bf = *(const short8*)&Wf[((t * 7 + ks) * 64 + lane) * 8];
                acc = __builtin_amdgcn_mfma_f32_16x16x32_bf16(af[ks], bf, acc, 0, 0, 0);
            }
#pragma unroll
            for (int rg = 0; rg < 4; ++rg)
                rs[rg] += fmaxf(acc[rg], 0.f);       // n>=200 adds exact 0
        }
#pragma unroll
        for (int off = 8; off >= 1; off >>= 1)
#pragma unroll
            for (int rg = 0; rg < 4; ++rg)
                rs[rg] += __shfl_xor(rs[rg], off, 16);
        if (ln == 0)
#pragma unroll
            for (int rg = 0; rg < 4; ++rg)
                rowsumW[wv][lq * 4 + rg] = rs[rg];
    }
    __syncthreads();

    // ---------- epilogue (all 16 rows real) ----------
    if (tid < TR) {
        const float s = rowsumW[0][tid] + rowsumW[1][tid]
                      + rowsumW[2][tid] + rowsumW[3][tid];
        const float logit = lrS[tid] + bglob[0] + s;
        out[row0 + tid] = 1.f / (1.f + expf(-logit));
    }
}

extern "C" void kernel_launch(void* const* d_in, const int* in_sizes, int n_in,
                              void* d_out, int out_size, void* d_ws, size_t ws_size,
                              hipStream_t stream) {
    const int*   feat_ids  = (const int*)  d_in[0];
    const float* feat_vals = (const float*)d_in[1];
    const float* w   = (const float*)d_in[2];
    const float* v   = (const float*)d_in[3];
    const float* b   = (const float*)d_in[4];
    const float* w0  = (const float*)d_in[5];
    const float* b0  = (const float*)d_in[6];
    const float* w1  = (const float*)d_in[7];
    const float* b1  = (const float*)d_in[8];
    const float* w2  = (const float*)d_in[9];
    const float* b2  = (const float*)d_in[10];
    float* out = (float*)d_out;
    short* ws  = (short*)d_ws;   // needs 99,840 * 2 B ~= 200 KB

    hipLaunchKernelGGL(nfm_prep_kernel, dim3(FRAG_BLOCKS), dim3(256),
                       0, stream, w0, w1, w2, ws);
    hipLaunchKernelGGL(nfm_main_kernel, dim3(NFM_B / TR), dim3(256), 0, stream,
                       feat_ids, feat_vals, v, w, b, b0, b1, b2, ws, out);
}